// Round 6
// baseline (290.001 us; speedup 1.0000x reference)
//
#include <hip/hip_runtime.h>
#include <hip/hip_cooperative_groups.h>

namespace cg = cooperative_groups;

#define DIM 32
#define NPB 128            // nodes per bucket
#define NPB_SHIFT 7
#define NPB_MASK 127
#define MAXB 1024          // max buckets supported
#define PCHUNK 2048        // edges per partition chunk (512 thr x 4)
#define CAPB 4096          // per-bucket packed capacity (>= 2x mean, gated host-side)
#define SCALE 262144.0f    // 2^18 fixed-point scale for int LDS accumulation
#define INV_SCALE (1.0f / 262144.0f)
#define TILE 8192          // legacy scan tile (generic fallback path)

__global__ void zero_i32_kernel(int* __restrict__ p, int n) {
    int t = blockIdx.x * blockDim.x + threadIdx.x;
    if (t < n) p[t] = 0;
}

// ====== fast path: fused cooperative {zero | partition | accumulate} =========

// --- partition one PCHUNK of edges into fixed-capacity bucket slices ---------
// LDS count (atomic return = local rank), ONE global atomicAdd per touched
// bucket reserves a contiguous slice, then scatter.
// packed = (src << NPB_SHIFT) | (dst & NPB_MASK). Order within a bucket is
// nondeterministic; accumulation is order-invariant integer adds, so the
// final result is deterministic.
__device__ __forceinline__ void partition_chunk(
        const int* __restrict__ src, const int* __restrict__ dst,
        int* __restrict__ gcur, int* __restrict__ packed,
        int n_edges, int nbuckets, int chunk,
        int* lcnt, int* lbase) {
    int t = threadIdx.x;
    for (int j = t; j < nbuckets; j += 512) lcnt[j] = 0;
    __syncthreads();

    int c0 = chunk * PCHUNK;
    int c1 = min(c0 + PCHUNK, n_edges);
    int i  = c0 + t * 4;

    int bb[4], pk[4], rr[4];       // static-indexed only (no scratch)
    int4 d, s;
    if (i + 3 < c1) {
        d = *(const int4*)(dst + i);
        s = *(const int4*)(src + i);
    } else {
        d.x = (i + 0 < c1) ? dst[i + 0] : -1;
        d.y = (i + 1 < c1) ? dst[i + 1] : -1;
        d.z = (i + 2 < c1) ? dst[i + 2] : -1;
        d.w = (i + 3 < c1) ? dst[i + 3] : -1;
        s.x = (i + 0 < c1) ? src[i + 0] : 0;
        s.y = (i + 1 < c1) ? src[i + 1] : 0;
        s.z = (i + 2 < c1) ? src[i + 2] : 0;
        s.w = (i + 3 < c1) ? src[i + 3] : 0;
    }
    bb[0] = (d.x >= 0) ? (d.x >> NPB_SHIFT) : -1;
    bb[1] = (d.y >= 0) ? (d.y >> NPB_SHIFT) : -1;
    bb[2] = (d.z >= 0) ? (d.z >> NPB_SHIFT) : -1;
    bb[3] = (d.w >= 0) ? (d.w >> NPB_SHIFT) : -1;
    pk[0] = (s.x << NPB_SHIFT) | (d.x & NPB_MASK);
    pk[1] = (s.y << NPB_SHIFT) | (d.y & NPB_MASK);
    pk[2] = (s.z << NPB_SHIFT) | (d.z & NPB_MASK);
    pk[3] = (s.w << NPB_SHIFT) | (d.w & NPB_MASK);

#pragma unroll
    for (int k = 0; k < 4; ++k)
        if (bb[k] >= 0) rr[k] = atomicAdd(&lcnt[bb[k]], 1);
    __syncthreads();
    for (int j = t; j < nbuckets; j += 512) {
        int c = lcnt[j];
        if (c > 0) lbase[j] = j * CAPB + atomicAdd(&gcur[j], c);
    }
    __syncthreads();
#pragma unroll
    for (int k = 0; k < 4; ++k)
        if (bb[k] >= 0) {
            int b = bb[k];
            int pos = lbase[b] + rr[k];
            if (pos < (b + 1) * CAPB) packed[pos] = pk[k];  // overflow guard
        }
    __syncthreads();   // lbase safe before next chunk's reservation
}

// Swizzled LDS accumulator index for node ld, quad q, component c:
//   addr = ld*32 + ((q + 8c + ld) & 31)
// Per ds_add instruction (fixed c): each edge-group's 8 q-lanes occupy 8
// consecutive banks rotated by the group's ld -> ~2-way avg (free).
__device__ __forceinline__ int aidx(int ld, int q, int c) {
    return (ld << 5) + ((q + (c << 3) + ld) & 31);
}

__device__ __forceinline__ void edge_accum(int* acc, int* scnt,
                                           const float4* __restrict__ x4,
                                           int p, int q) {
    int ld   = p & NPB_MASK;
    int srow = p >> NPB_SHIFT;
    float4 v = x4[srow * 8 + q];   // 8 lanes = one 128B row line
    atomicAdd(&acc[aidx(ld, q, 0)], __float2int_rn(v.x * SCALE));
    atomicAdd(&acc[aidx(ld, q, 1)], __float2int_rn(v.y * SCALE));
    atomicAdd(&acc[aidx(ld, q, 2)], __float2int_rn(v.z * SCALE));
    atomicAdd(&acc[aidx(ld, q, 3)], __float2int_rn(v.w * SCALE));
    if (q == 0) atomicAdd(&scnt[ld], 1);
}

// --- accumulate one 128-node bucket ------------------------------------------
// Divergence-free edge-parallel loop: 8 lanes per edge, each lane loads one
// float4 of x[src], converts to fixed-point, 4 native ds_add_u32.
__device__ __forceinline__ void accum_bucket(
        const float4* __restrict__ x4, const int* __restrict__ gcur,
        const int* __restrict__ packed, float4* __restrict__ out4,
        int n_nodes, int b, int* acc, int* scnt) {
    int t = threadIdx.x;
    for (int j = t; j < NPB * DIM; j += 512) acc[j] = 0;
    if (t < NPB) scnt[t] = 0;
    __syncthreads();

    int ecnt = min(gcur[b], CAPB);       // matches partition overflow guard
    const int* seg = packed + (size_t)b * CAPB;

    int g = t >> 3;                      // edge group 0..63
    int q = t & 7;                       // feature quad
    int e = g;
    for (; e + 192 < ecnt; e += 256) {   // 4 gathers in flight
        int p0 = seg[e];
        int p1 = seg[e + 64];
        int p2 = seg[e + 128];
        int p3 = seg[e + 192];
        edge_accum(acc, scnt, x4, p0, q);
        edge_accum(acc, scnt, x4, p1, q);
        edge_accum(acc, scnt, x4, p2, q);
        edge_accum(acc, scnt, x4, p3, q);
    }
    for (; e < ecnt; e += 64)
        edge_accum(acc, scnt, x4, seg[e], q);
    __syncthreads();

    int n0 = b << NPB_SHIFT;
    for (int j = t; j < NPB * 8; j += 512) {
        int node = j >> 3;
        int qq   = j & 7;
        int gn   = n0 + node;
        if (gn < n_nodes) {
            float inv = 1.0f / ((float)max(scnt[node], 1)) * INV_SCALE;
            float4 r;
            r.x = (float)acc[aidx(node, qq, 0)] * inv;
            r.y = (float)acc[aidx(node, qq, 1)] * inv;
            r.z = (float)acc[aidx(node, qq, 2)] * inv;
            r.w = (float)acc[aidx(node, qq, 3)] * inv;
            out4[(size_t)gn * 8 + qq] = r;
        }
    }
    __syncthreads();   // acc safe before next bucket's zeroing
}

// --- fused cooperative kernel: one dispatch, two grid syncs ------------------
__global__ void __launch_bounds__(512)
fused_graph_kernel(const float4* __restrict__ x4, const int* __restrict__ src,
                   const int* __restrict__ dst, int* __restrict__ gcur,
                   int* __restrict__ packed, float4* __restrict__ out4,
                   int n_nodes, int n_edges, int nbuckets, int nchunks) {
    __shared__ int lcnt[MAXB];
    __shared__ int lbase[MAXB];
    __shared__ int acc[NPB * DIM];
    __shared__ int scnt[NPB];

    cg::grid_group grid = cg::this_grid();

    // phase 0: zero bucket cursors
    for (int j = blockIdx.x * 512 + threadIdx.x; j < nbuckets;
         j += gridDim.x * 512)
        gcur[j] = 0;
    grid.sync();

    // phase 1: partition
    for (int c = blockIdx.x; c < nchunks; c += gridDim.x)
        partition_chunk(src, dst, gcur, packed, n_edges, nbuckets, c,
                        lcnt, lbase);
    grid.sync();

    // phase 2: accumulate
    for (int b = blockIdx.x; b < nbuckets; b += gridDim.x)
        accum_bucket(x4, gcur, packed, out4, n_nodes, b, acc, scnt);
}

// --- standalone wrappers (fallback if cooperative launch is unavailable) -----
__global__ void __launch_bounds__(512)
partition_cap_kernel(const int* __restrict__ src, const int* __restrict__ dst,
                     int* __restrict__ gcur, int* __restrict__ packed,
                     int n_edges, int nbuckets) {
    __shared__ int lcnt[MAXB];
    __shared__ int lbase[MAXB];
    partition_chunk(src, dst, gcur, packed, n_edges, nbuckets, blockIdx.x,
                    lcnt, lbase);
}

__global__ void __launch_bounds__(512)
accum_int_kernel(const float4* __restrict__ x4, const int* __restrict__ gcur,
                 const int* __restrict__ packed, float4* __restrict__ out4,
                 int n_nodes) {
    __shared__ int acc[NPB * DIM];
    __shared__ int scnt[NPB];
    accum_bucket(x4, gcur, packed, out4, n_nodes, blockIdx.x, acc, scnt);
}

// ================= generic fallback: sorted (pull) path =================

__global__ void hist_kernel(const int* __restrict__ dst, int* __restrict__ counts,
                            int n_edges) {
    int t = blockIdx.x * blockDim.x + threadIdx.x;
    if (t < n_edges) atomicAdd(&counts[dst[t]], 1);
}

__global__ void scan_part1(const int* __restrict__ counts,
                           int* __restrict__ block_sums, int n) {
    __shared__ int sh[256];
    int base = blockIdx.x * TILE + threadIdx.x * 32;
    int s = 0;
#pragma unroll
    for (int i = 0; i < 32; ++i) {
        int idx = base + i;
        if (idx < n) s += counts[idx];
    }
    sh[threadIdx.x] = s;
    __syncthreads();
    for (int off = 128; off > 0; off >>= 1) {
        if (threadIdx.x < off) sh[threadIdx.x] += sh[threadIdx.x + off];
        __syncthreads();
    }
    if (threadIdx.x == 0) block_sums[blockIdx.x] = sh[0];
}

__global__ void scan_part2(int* __restrict__ block_sums, int nb) {
    if (blockIdx.x == 0 && threadIdx.x == 0) {
        int run = 0;
        for (int i = 0; i < nb; ++i) {
            int v = block_sums[i];
            block_sums[i] = run;
            run += v;
        }
    }
}

__global__ void scan_part3(const int* __restrict__ counts,
                           const int* __restrict__ block_sums,
                           int* __restrict__ offsets, int n) {
    __shared__ int sh[256];
    int tid = threadIdx.x;
    int base = blockIdx.x * TILE + tid * 32;
    int local[32];
    int s = 0;
#pragma unroll
    for (int i = 0; i < 32; ++i) {
        int idx = base + i;
        int v = (idx < n) ? counts[idx] : 0;
        local[i] = v;
        s += v;
    }
    sh[tid] = s;
    __syncthreads();
    for (int off = 1; off < 256; off <<= 1) {
        int v = (tid >= off) ? sh[tid - off] : 0;
        __syncthreads();
        sh[tid] += v;
        __syncthreads();
    }
    int run = block_sums[blockIdx.x] + ((tid == 0) ? 0 : sh[tid - 1]);
#pragma unroll
    for (int i = 0; i < 32; ++i) {
        int idx = base + i;
        if (idx < n) offsets[idx] = run;
        run += local[i];
    }
}

__global__ void scatter_sort_kernel(const int* __restrict__ src,
                                    const int* __restrict__ dst,
                                    int* __restrict__ cursors,
                                    int* __restrict__ sorted_src,
                                    int n_edges) {
    int t = blockIdx.x * blockDim.x + threadIdx.x;
    if (t < n_edges) {
        int pos = atomicAdd(&cursors[dst[t]], 1);
        sorted_src[pos] = src[t];
    }
}

__device__ inline void f4add(float4& a, float4 v) {
    a.x += v.x; a.y += v.y; a.z += v.z; a.w += v.w;
}

__global__ void aggregate_kernel(const float* __restrict__ x,
                                 const int* __restrict__ seg_end,
                                 const int* __restrict__ sorted_src,
                                 float4* __restrict__ out,
                                 int n_nodes) {
    int t = blockIdx.x * blockDim.x + threadIdx.x;
    int n = t >> 3;
    if (n >= n_nodes) return;
    int q = t & 7;
    int end   = seg_end[n];
    int start = (n == 0) ? 0 : seg_end[n - 1];
    const float4* x4 = (const float4*)x;
    float4 acc0 = make_float4(0.f, 0.f, 0.f, 0.f);
    float4 acc1 = make_float4(0.f, 0.f, 0.f, 0.f);
    int k = start;
    for (; k + 1 < end; k += 2) {
        int s0 = sorted_src[k];
        int s1 = sorted_src[k + 1];
        f4add(acc0, x4[s0 * 8 + q]);
        f4add(acc1, x4[s1 * 8 + q]);
    }
    if (k < end) f4add(acc0, x4[sorted_src[k] * 8 + q]);
    float inv = 1.0f / (float)max(end - start, 1);
    float4 r;
    r.x = (acc0.x + acc1.x) * inv;
    r.y = (acc0.y + acc1.y) * inv;
    r.z = (acc0.z + acc1.z) * inv;
    r.w = (acc0.w + acc1.w) * inv;
    out[n * 8 + q] = r;
}

// ================= launch =================

extern "C" void kernel_launch(void* const* d_in, const int* in_sizes, int n_in,
                              void* d_out, int out_size, void* d_ws, size_t ws_size,
                              hipStream_t stream) {
    const float* x   = (const float*)d_in[0];
    const int*   src = (const int*)d_in[1];
    const int*   dst = (const int*)d_in[2];
    float* out = (float*)d_out;

    int n_nodes = in_sizes[0] / DIM;
    int n_edges = in_sizes[1];

    int nbuckets = (n_nodes + NPB - 1) >> NPB_SHIFT;
    int nchunks  = (n_edges + PCHUNK - 1) / PCHUNK;
    size_t need = ((size_t)nbuckets * (CAPB + 1)) * sizeof(int);
    bool fast_ok = (n_nodes < (1 << 24)) && (nbuckets <= MAXB) &&
                   ((size_t)n_edges * 2 <= (size_t)nbuckets * CAPB) &&
                   (ws_size >= need);

    if (fast_ok) {
        int* gcur   = (int*)d_ws;            // [nbuckets] cursors (-> counts)
        int* packed = gcur + nbuckets;       // [nbuckets * CAPB]

        // size cooperative grid to guaranteed co-residency
        int dev = 0;
        (void)hipGetDevice(&dev);
        int numCU = 256;
        (void)hipDeviceGetAttribute(&numCU,
                                    hipDeviceAttributeMultiprocessorCount, dev);
        int occ = 0;
        hipError_t oe = hipOccupancyMaxActiveBlocksPerMultiprocessor(
            &occ, fused_graph_kernel, 512, 0);
        if (oe != hipSuccess || occ <= 0) occ = 2;   // conservative
        long maxco = (long)occ * (long)numCU;
        int grid = (int)((maxco < (long)nbuckets) ? maxco : (long)nbuckets);
        if (grid < 1) grid = 1;

        const float4* x4p = (const float4*)x;
        float4* outp = (float4*)out;
        void* args[] = {(void*)&x4p, (void*)&src, (void*)&dst, (void*)&gcur,
                        (void*)&packed, (void*)&outp, (void*)&n_nodes,
                        (void*)&n_edges, (void*)&nbuckets, (void*)&nchunks};
        hipError_t ce = hipLaunchCooperativeKernel(
            (const void*)fused_graph_kernel, dim3(grid), dim3(512), args, 0,
            stream);
        if (ce != hipSuccess) {
            // fallback: proven 3-kernel pipeline (same math)
            zero_i32_kernel<<<(nbuckets + 255) / 256, 256, 0, stream>>>(
                gcur, nbuckets);
            partition_cap_kernel<<<nchunks, 512, 0, stream>>>(src, dst, gcur,
                                                              packed, n_edges,
                                                              nbuckets);
            accum_int_kernel<<<nbuckets, 512, 0, stream>>>((const float4*)x,
                                                           gcur, packed,
                                                           (float4*)out,
                                                           n_nodes);
        }
    } else {
        // generic fallback: dst-sorted pull path (verified pipeline)
        int nb = (n_nodes + TILE - 1) / TILE;
        int* counts     = (int*)d_ws;
        int* offsets    = counts + n_nodes;
        int* sorted_src = offsets + n_nodes;
        int* block_sums = sorted_src + n_edges;

        zero_i32_kernel<<<(n_nodes + 255) / 256, 256, 0, stream>>>(counts,
                                                                   n_nodes);
        int eb = (n_edges + 255) / 256;
        hist_kernel<<<eb, 256, 0, stream>>>(dst, counts, n_edges);
        scan_part1<<<nb, 256, 0, stream>>>(counts, block_sums, n_nodes);
        scan_part2<<<1, 64, 0, stream>>>(block_sums, nb);
        scan_part3<<<nb, 256, 0, stream>>>(counts, block_sums, offsets, n_nodes);
        scatter_sort_kernel<<<eb, 256, 0, stream>>>(src, dst, offsets,
                                                    sorted_src, n_edges);
        int athreads = n_nodes * 8;
        int ab = (athreads + 255) / 256;
        aggregate_kernel<<<ab, 256, 0, stream>>>(x, offsets, sorted_src,
                                                 (float4*)out, n_nodes);
    }
}

// Round 7
// 118.482 us; speedup vs baseline: 2.4476x; 2.4476x over previous
//
#include <hip/hip_runtime.h>

#define DIM 32
#define NPB 128            // nodes per bucket
#define NPB_SHIFT 7
#define NPB_MASK 127
#define MAXB 1024          // max buckets supported
#define PCHUNK 8192        // edges per partition block (512 thr x 16)
#define CAPB 4096          // per-bucket packed capacity (>= 2x mean, gated host-side)
#define CURPAD 16          // gcur stride in ints (one cursor per 64B line)
#define SCALE 262144.0f    // 2^18 fixed-point scale for int LDS accumulation
#define INV_SCALE (1.0f / 262144.0f)
#define TILE 8192          // legacy scan tile (generic fallback path)

__global__ void zero_i32_kernel(int* __restrict__ p, int n) {
    int t = blockIdx.x * blockDim.x + threadIdx.x;
    if (t < n) p[t] = 0;
}

// ====== fast path: fixed-capacity bucket partition + int-LDS-atomic accum ====
// 3 nodes in the graph: memset(gcur) -> partition -> accumulate.
// ~94us of dur_us is fixed harness overhead (fills); these kernels are ~25us.

// Partition edges into fixed-capacity bucket regions packed[b*CAPB ...].
// Per block: stash 16 edges/thread in registers, LDS count (atomic return =
// local rank), ONE padded global atomicAdd per touched bucket to reserve a
// contiguous slice, then scatter. packed = (src << NPB_SHIFT) | (dst & MASK).
// Order within a bucket is nondeterministic; accumulation is order-invariant
// integer adds, so the final result is deterministic.
__global__ void __launch_bounds__(512)
partition_cap_kernel(const int* __restrict__ src, const int* __restrict__ dst,
                     int* __restrict__ gcur, int* __restrict__ packed,
                     int n_edges, int nbuckets) {
    __shared__ int lcnt[MAXB];
    __shared__ int lbase[MAXB];
    int t = threadIdx.x;
    for (int j = t; j < nbuckets; j += 512) lcnt[j] = 0;
    __syncthreads();

    int c0 = blockIdx.x * PCHUNK;
    int c1 = min(c0 + PCHUNK, n_edges);

    int bb[16], pk[16], rr[16];   // static-indexed only (no scratch)
#pragma unroll
    for (int g = 0; g < 4; ++g) {
        int i = c0 + g * 2048 + t * 4;
        int4 d, s;
        if (i + 3 < c1) {
            d = *(const int4*)(dst + i);
            s = *(const int4*)(src + i);
        } else {
            d.x = (i + 0 < c1) ? dst[i + 0] : -1;
            d.y = (i + 1 < c1) ? dst[i + 1] : -1;
            d.z = (i + 2 < c1) ? dst[i + 2] : -1;
            d.w = (i + 3 < c1) ? dst[i + 3] : -1;
            s.x = (i + 0 < c1) ? src[i + 0] : 0;
            s.y = (i + 1 < c1) ? src[i + 1] : 0;
            s.z = (i + 2 < c1) ? src[i + 2] : 0;
            s.w = (i + 3 < c1) ? src[i + 3] : 0;
        }
        bb[g * 4 + 0] = (d.x >= 0) ? (d.x >> NPB_SHIFT) : -1;
        bb[g * 4 + 1] = (d.y >= 0) ? (d.y >> NPB_SHIFT) : -1;
        bb[g * 4 + 2] = (d.z >= 0) ? (d.z >> NPB_SHIFT) : -1;
        bb[g * 4 + 3] = (d.w >= 0) ? (d.w >> NPB_SHIFT) : -1;
        pk[g * 4 + 0] = (s.x << NPB_SHIFT) | (d.x & NPB_MASK);
        pk[g * 4 + 1] = (s.y << NPB_SHIFT) | (d.y & NPB_MASK);
        pk[g * 4 + 2] = (s.z << NPB_SHIFT) | (d.z & NPB_MASK);
        pk[g * 4 + 3] = (s.w << NPB_SHIFT) | (d.w & NPB_MASK);
    }
#pragma unroll
    for (int k = 0; k < 16; ++k)
        if (bb[k] >= 0) rr[k] = atomicAdd(&lcnt[bb[k]], 1);
    __syncthreads();
    for (int j = t; j < nbuckets; j += 512) {
        int c = lcnt[j];
        if (c > 0) lbase[j] = j * CAPB + atomicAdd(&gcur[j * CURPAD], c);
    }
    __syncthreads();
#pragma unroll
    for (int k = 0; k < 16; ++k)
        if (bb[k] >= 0) {
            int b = bb[k];
            int pos = lbase[b] + rr[k];
            if (pos < (b + 1) * CAPB) packed[pos] = pk[k];  // overflow guard
        }
}

// Swizzled LDS accumulator index for node ld, quad q, component c:
//   addr = ld*32 + ((q + 8c + ld) & 31)
// Per ds_add instruction (fixed c): each edge-group's 8 q-lanes occupy 8
// consecutive banks rotated by the group's ld -> ~2-way avg (free).
__device__ __forceinline__ int aidx(int ld, int q, int c) {
    return (ld << 5) + ((q + (c << 3) + ld) & 31);
}

__device__ __forceinline__ void edge_accum(int* acc, int* scnt,
                                           const float4* __restrict__ x4,
                                           int p, int q) {
    int ld   = p & NPB_MASK;
    int srow = p >> NPB_SHIFT;
    float4 v = x4[srow * 8 + q];   // 8 lanes = one 128B row line
    atomicAdd(&acc[aidx(ld, q, 0)], __float2int_rn(v.x * SCALE));
    atomicAdd(&acc[aidx(ld, q, 1)], __float2int_rn(v.y * SCALE));
    atomicAdd(&acc[aidx(ld, q, 2)], __float2int_rn(v.z * SCALE));
    atomicAdd(&acc[aidx(ld, q, 3)], __float2int_rn(v.w * SCALE));
    if (q == 0) atomicAdd(&scnt[ld], 1);
}

// One 512-thread block per 128-node bucket. Divergence-free edge-parallel
// loop: 8 lanes per edge, each lane loads one float4 of x[src], converts to
// fixed-point, 4 native ds_add_u32 into the swizzled accumulator.
__global__ void __launch_bounds__(512)
accum_int_kernel(const float4* __restrict__ x4,
                 const int* __restrict__ gcur,
                 const int* __restrict__ packed,
                 float4* __restrict__ out4, int n_nodes) {
    __shared__ int acc[NPB * DIM];   // 16 KB
    __shared__ int scnt[NPB];
    int b = blockIdx.x;
    int t = threadIdx.x;
    for (int j = t; j < NPB * DIM; j += 512) acc[j] = 0;
    if (t < NPB) scnt[t] = 0;
    __syncthreads();

    int ecnt = min(gcur[b * CURPAD], CAPB);   // matches partition guard
    const int* seg = packed + (size_t)b * CAPB;

    int g = t >> 3;                      // edge group 0..63
    int q = t & 7;                       // feature quad
    int e = g;
    for (; e + 192 < ecnt; e += 256) {   // 4 gathers in flight
        int p0 = seg[e];
        int p1 = seg[e + 64];
        int p2 = seg[e + 128];
        int p3 = seg[e + 192];
        edge_accum(acc, scnt, x4, p0, q);
        edge_accum(acc, scnt, x4, p1, q);
        edge_accum(acc, scnt, x4, p2, q);
        edge_accum(acc, scnt, x4, p3, q);
    }
    for (; e < ecnt; e += 64)
        edge_accum(acc, scnt, x4, seg[e], q);
    __syncthreads();

    int n0 = b << NPB_SHIFT;
    for (int j = t; j < NPB * 8; j += 512) {
        int node = j >> 3;
        int qq   = j & 7;
        int gn   = n0 + node;
        if (gn < n_nodes) {
            float inv = 1.0f / ((float)max(scnt[node], 1)) * INV_SCALE;
            float4 r;
            r.x = (float)acc[aidx(node, qq, 0)] * inv;
            r.y = (float)acc[aidx(node, qq, 1)] * inv;
            r.z = (float)acc[aidx(node, qq, 2)] * inv;
            r.w = (float)acc[aidx(node, qq, 3)] * inv;
            out4[(size_t)gn * 8 + qq] = r;
        }
    }
}

// ================= generic fallback: sorted (pull) path =================

__global__ void hist_kernel(const int* __restrict__ dst, int* __restrict__ counts,
                            int n_edges) {
    int t = blockIdx.x * blockDim.x + threadIdx.x;
    if (t < n_edges) atomicAdd(&counts[dst[t]], 1);
}

__global__ void scan_part1(const int* __restrict__ counts,
                           int* __restrict__ block_sums, int n) {
    __shared__ int sh[256];
    int base = blockIdx.x * TILE + threadIdx.x * 32;
    int s = 0;
#pragma unroll
    for (int i = 0; i < 32; ++i) {
        int idx = base + i;
        if (idx < n) s += counts[idx];
    }
    sh[threadIdx.x] = s;
    __syncthreads();
    for (int off = 128; off > 0; off >>= 1) {
        if (threadIdx.x < off) sh[threadIdx.x] += sh[threadIdx.x + off];
        __syncthreads();
    }
    if (threadIdx.x == 0) block_sums[blockIdx.x] = sh[0];
}

__global__ void scan_part2(int* __restrict__ block_sums, int nb) {
    if (blockIdx.x == 0 && threadIdx.x == 0) {
        int run = 0;
        for (int i = 0; i < nb; ++i) {
            int v = block_sums[i];
            block_sums[i] = run;
            run += v;
        }
    }
}

__global__ void scan_part3(const int* __restrict__ counts,
                           const int* __restrict__ block_sums,
                           int* __restrict__ offsets, int n) {
    __shared__ int sh[256];
    int tid = threadIdx.x;
    int base = blockIdx.x * TILE + tid * 32;
    int local[32];
    int s = 0;
#pragma unroll
    for (int i = 0; i < 32; ++i) {
        int idx = base + i;
        int v = (idx < n) ? counts[idx] : 0;
        local[i] = v;
        s += v;
    }
    sh[tid] = s;
    __syncthreads();
    for (int off = 1; off < 256; off <<= 1) {
        int v = (tid >= off) ? sh[tid - off] : 0;
        __syncthreads();
        sh[tid] += v;
        __syncthreads();
    }
    int run = block_sums[blockIdx.x] + ((tid == 0) ? 0 : sh[tid - 1]);
#pragma unroll
    for (int i = 0; i < 32; ++i) {
        int idx = base + i;
        if (idx < n) offsets[idx] = run;
        run += local[i];
    }
}

__global__ void scatter_sort_kernel(const int* __restrict__ src,
                                    const int* __restrict__ dst,
                                    int* __restrict__ cursors,
                                    int* __restrict__ sorted_src,
                                    int n_edges) {
    int t = blockIdx.x * blockDim.x + threadIdx.x;
    if (t < n_edges) {
        int pos = atomicAdd(&cursors[dst[t]], 1);
        sorted_src[pos] = src[t];
    }
}

__device__ inline void f4add(float4& a, float4 v) {
    a.x += v.x; a.y += v.y; a.z += v.z; a.w += v.w;
}

__global__ void aggregate_kernel(const float* __restrict__ x,
                                 const int* __restrict__ seg_end,
                                 const int* __restrict__ sorted_src,
                                 float4* __restrict__ out,
                                 int n_nodes) {
    int t = blockIdx.x * blockDim.x + threadIdx.x;
    int n = t >> 3;
    if (n >= n_nodes) return;
    int q = t & 7;
    int end   = seg_end[n];
    int start = (n == 0) ? 0 : seg_end[n - 1];
    const float4* x4 = (const float4*)x;
    float4 acc0 = make_float4(0.f, 0.f, 0.f, 0.f);
    float4 acc1 = make_float4(0.f, 0.f, 0.f, 0.f);
    int k = start;
    for (; k + 1 < end; k += 2) {
        int s0 = sorted_src[k];
        int s1 = sorted_src[k + 1];
        f4add(acc0, x4[s0 * 8 + q]);
        f4add(acc1, x4[s1 * 8 + q]);
    }
    if (k < end) f4add(acc0, x4[sorted_src[k] * 8 + q]);
    float inv = 1.0f / (float)max(end - start, 1);
    float4 r;
    r.x = (acc0.x + acc1.x) * inv;
    r.y = (acc0.y + acc1.y) * inv;
    r.z = (acc0.z + acc1.z) * inv;
    r.w = (acc0.w + acc1.w) * inv;
    out[n * 8 + q] = r;
}

// ================= launch =================

extern "C" void kernel_launch(void* const* d_in, const int* in_sizes, int n_in,
                              void* d_out, int out_size, void* d_ws, size_t ws_size,
                              hipStream_t stream) {
    const float* x   = (const float*)d_in[0];
    const int*   src = (const int*)d_in[1];
    const int*   dst = (const int*)d_in[2];
    float* out = (float*)d_out;

    int n_nodes = in_sizes[0] / DIM;
    int n_edges = in_sizes[1];

    int nbuckets = (n_nodes + NPB - 1) >> NPB_SHIFT;
    int pblocks  = (n_edges + PCHUNK - 1) / PCHUNK;
    size_t cur_ints = (size_t)nbuckets * CURPAD;
    size_t need = (cur_ints + (size_t)nbuckets * CAPB) * sizeof(int);
    bool fast_ok = (n_nodes < (1 << 24)) && (nbuckets <= MAXB) &&
                   ((size_t)n_edges * 2 <= (size_t)nbuckets * CAPB) &&
                   (ws_size >= need);

    if (fast_ok) {
        int* gcur   = (int*)d_ws;            // [nbuckets*CURPAD] padded cursors
        int* packed = gcur + cur_ints;       // [nbuckets * CAPB]

        hipMemsetAsync(gcur, 0, cur_ints * sizeof(int), stream);
        if (pblocks > 0)
            partition_cap_kernel<<<pblocks, 512, 0, stream>>>(src, dst, gcur,
                                                              packed, n_edges,
                                                              nbuckets);
        accum_int_kernel<<<nbuckets, 512, 0, stream>>>((const float4*)x,
                                                       gcur, packed,
                                                       (float4*)out, n_nodes);
    } else {
        // generic fallback: dst-sorted pull path (verified pipeline)
        int nb = (n_nodes + TILE - 1) / TILE;
        int* counts     = (int*)d_ws;
        int* offsets    = counts + n_nodes;
        int* sorted_src = offsets + n_nodes;
        int* block_sums = sorted_src + n_edges;

        zero_i32_kernel<<<(n_nodes + 255) / 256, 256, 0, stream>>>(counts,
                                                                   n_nodes);
        int eb = (n_edges + 255) / 256;
        hist_kernel<<<eb, 256, 0, stream>>>(dst, counts, n_edges);
        scan_part1<<<nb, 256, 0, stream>>>(counts, block_sums, n_nodes);
        scan_part2<<<1, 64, 0, stream>>>(block_sums, nb);
        scan_part3<<<nb, 256, 0, stream>>>(counts, block_sums, offsets, n_nodes);
        scatter_sort_kernel<<<eb, 256, 0, stream>>>(src, dst, offsets,
                                                    sorted_src, n_edges);
        int athreads = n_nodes * 8;
        int ab = (athreads + 255) / 256;
        aggregate_kernel<<<ab, 256, 0, stream>>>(x, offsets, sorted_src,
                                                 (float4*)out, n_nodes);
    }
}